// Round 1
// baseline (285.026 us; speedup 1.0000x reference)
//
#include <hip/hip_runtime.h>

typedef _Float16 f16;
typedef _Float16 h8 __attribute__((ext_vector_type(8)));
typedef float f4 __attribute__((ext_vector_type(4)));

#define B_ 4
#define S_ 2048
#define D_ 1024
#define H_ 1024

// ---------------- fp32 -> fp16 cast, vectorized ----------------
__global__ __launch_bounds__(256) void cast_f32_f16(const float* __restrict__ in,
                                                    f16* __restrict__ out, long n8) {
  long i = blockIdx.x * 256L + threadIdx.x;
  const long stride = (long)gridDim.x * 256L;
  for (; i < n8; i += stride) {
    float4 u = *(const float4*)(in + i * 8);
    float4 v = *(const float4*)(in + i * 8 + 4);
    h8 o;
    o[0] = (f16)u.x; o[1] = (f16)u.y; o[2] = (f16)u.z; o[3] = (f16)u.w;
    o[4] = (f16)v.x; o[5] = (f16)v.y; o[6] = (f16)v.z; o[7] = (f16)v.w;
    *(h8*)(out + i * 8) = o;
  }
}

// ---------------- GEMM: C = A * B^T ----------------
// A: [M,K] f16 row-major; B: [N,K] f16 row-major (K contiguous both sides).
// OUT_MODE 0: fp32 C[m*N+n]   (scores, final out)
// OUT_MODE 1: f16  C[m*N+n]   (Q, K projections)
// OUT_MODE 2: f16 transposed per-batch: C[(m>>11)][n][m&2047]  (V^T projection)
// grid: (M/128, N/128, batches); per-batch strides sA/sB/sC in elements.
#define TILE 128
#define BK 32
#define PADK 40  // 40 f16 = 80B rows: bank-uniform for b128 access

template <int OUT_MODE>
__global__ __launch_bounds__(256) void gemm_abt(const f16* __restrict__ A,
                                                const f16* __restrict__ Bm,
                                                void* __restrict__ C,
                                                int M, int N, int K,
                                                long sA, long sB, long sC) {
  const int bz = blockIdx.z;
  A += (long)bz * sA;
  Bm += (long)bz * sB;

  __shared__ __align__(16) f16 lA[TILE][PADK];
  __shared__ __align__(16) f16 lB[TILE][PADK];

  const int tid = threadIdx.x;
  const int lane = tid & 63;
  const int wv = tid >> 6;
  const int wr = wv >> 1, wc = wv & 1;  // 2x2 waves over the 128x128 tile
  const int m0 = blockIdx.x * TILE;
  const int n0 = blockIdx.y * TILE;

  // staging: each thread moves 2x 16B chunks per matrix per K-step
  const int r0 = tid >> 2;            // 0..63
  const int c0 = (tid & 3) * 8;       // 0,8,16,24

  const int fr = lane & 15;
  const int kg = (lane >> 4) * 8;

  f4 acc[4][4] = {};

  for (int k0 = 0; k0 < K; k0 += BK) {
    h8 a0 = *(const h8*)(A + (long)(m0 + r0) * K + k0 + c0);
    h8 a1 = *(const h8*)(A + (long)(m0 + r0 + 64) * K + k0 + c0);
    h8 b0 = *(const h8*)(Bm + (long)(n0 + r0) * K + k0 + c0);
    h8 b1 = *(const h8*)(Bm + (long)(n0 + r0 + 64) * K + k0 + c0);
    __syncthreads();  // previous iteration's fragment reads complete
    *(h8*)&lA[r0][c0] = a0;
    *(h8*)&lA[r0 + 64][c0] = a1;
    *(h8*)&lB[r0][c0] = b0;
    *(h8*)&lB[r0 + 64][c0] = b1;
    __syncthreads();

    h8 af[4], bf[4];
#pragma unroll
    for (int i = 0; i < 4; ++i) {
      af[i] = *(const h8*)&lA[wr * 64 + i * 16 + fr][kg];
      bf[i] = *(const h8*)&lB[wc * 64 + i * 16 + fr][kg];
    }
#pragma unroll
    for (int mi = 0; mi < 4; ++mi)
#pragma unroll
      for (int ni = 0; ni < 4; ++ni)
        acc[mi][ni] = __builtin_amdgcn_mfma_f32_16x16x32_f16(af[mi], bf[ni], acc[mi][ni], 0, 0, 0);
  }

  // epilogue: C/D layout (measured): col = lane&15, row = (lane>>4)*4 + reg
  const int fq = (lane >> 4) * 4;
#pragma unroll
  for (int mi = 0; mi < 4; ++mi) {
#pragma unroll
    for (int ni = 0; ni < 4; ++ni) {
#pragma unroll
      for (int i = 0; i < 4; ++i) {
        const int row = m0 + wr * 64 + mi * 16 + fq + i;
        const int col = n0 + wc * 64 + ni * 16 + fr;
        const float val = acc[mi][ni][i];
        if constexpr (OUT_MODE == 0) {
          float* Cp = (float*)C + (long)bz * sC;
          Cp[(long)row * N + col] = val;
        } else if constexpr (OUT_MODE == 1) {
          f16* Cp = (f16*)C + (long)bz * sC;
          Cp[(long)row * N + col] = (f16)val;
        } else {
          f16* Cp = (f16*)C;
          const int b = row >> 11, sr = row & 2047;  // S_=2048 rows per batch
          Cp[((long)b * N + col) * 2048 + sr] = (f16)val;
        }
      }
    }
  }
}

// ---------------- fused scale + mask + softmax, scores f32 -> P f16 ----------------
__global__ __launch_bounds__(256) void softmax_rows(const float* __restrict__ Sc,
                                                    const float* __restrict__ mask,
                                                    f16* __restrict__ P, float scale) {
  const long row = blockIdx.x;  // b*S + q, 8192 rows of length 2048
  const float* s = Sc + row * (long)S_;
  const float* mk = mask + row * (long)S_;
  const int t = threadIdx.x;

  float4 a0 = *(const float4*)(s + t * 8);
  float4 a1 = *(const float4*)(s + t * 8 + 4);
  float4 b0 = *(const float4*)(mk + t * 8);
  float4 b1 = *(const float4*)(mk + t * 8 + 4);
  float v[8] = {a0.x * scale + b0.x, a0.y * scale + b0.y,
                a0.z * scale + b0.z, a0.w * scale + b0.w,
                a1.x * scale + b1.x, a1.y * scale + b1.y,
                a1.z * scale + b1.z, a1.w * scale + b1.w};

  float mx = v[0];
#pragma unroll
  for (int j = 1; j < 8; ++j) mx = fmaxf(mx, v[j]);
  for (int o = 32; o > 0; o >>= 1) mx = fmaxf(mx, __shfl_xor(mx, o));

  __shared__ float redm[4];
  __shared__ float reds[4];
  const int w = t >> 6;
  if ((t & 63) == 0) redm[w] = mx;
  __syncthreads();
  mx = fmaxf(fmaxf(redm[0], redm[1]), fmaxf(redm[2], redm[3]));

  float e[8];
  float sum = 0.f;
#pragma unroll
  for (int j = 0; j < 8; ++j) { e[j] = __expf(v[j] - mx); sum += e[j]; }
  for (int o = 32; o > 0; o >>= 1) sum += __shfl_xor(sum, o);
  if ((t & 63) == 0) reds[w] = sum;
  __syncthreads();
  sum = reds[0] + reds[1] + reds[2] + reds[3];
  const float inv = 1.0f / sum;

  h8 o;
#pragma unroll
  for (int j = 0; j < 8; ++j) o[j] = (f16)(e[j] * inv);
  *(h8*)(P + row * (long)S_ + t * 8) = o;
}

extern "C" void kernel_launch(void* const* d_in, const int* in_sizes, int n_in,
                              void* d_out, int out_size, void* d_ws, size_t ws_size,
                              hipStream_t stream) {
  const float* x1 = (const float*)d_in[0];
  const float* x2 = (const float*)d_in[1];
  const float* x3 = (const float*)d_in[2];
  const float* mask = (const float*)d_in[3];
  const float* Wq = (const float*)d_in[4];
  const float* Wk = (const float*)d_in[5];
  const float* Wv = (const float*)d_in[6];

  const long nx = (long)B_ * S_ * D_;        // 8388608
  const long nw = (long)H_ * D_;             // 1048576
  const long nqkv = (long)B_ * S_ * H_;      // 8388608
  const long nsc = (long)B_ * S_ * S_;       // 16777216

  char* ws = (char*)d_ws;
  f16* x1h = (f16*)ws; ws += nx * 2;
  f16* x2h = (f16*)ws; ws += nx * 2;
  f16* x3h = (f16*)ws; ws += nx * 2;
  f16* wqh = (f16*)ws; ws += nw * 2;
  f16* wkh = (f16*)ws; ws += nw * 2;
  f16* wvh = (f16*)ws; ws += nw * 2;
  f16* qh  = (f16*)ws; ws += nqkv * 2;
  f16* kh  = (f16*)ws; ws += nqkv * 2;
  f16* vth = (f16*)ws; ws += nqkv * 2;   // [b][h][s]
  float* sc = (float*)ws; ws += nsc * 4;
  f16* ph  = (f16*)ws; ws += nsc * 2;    // ~208 MB total

  auto cgrid = [](long n8) {
    long b = (n8 + 255) / 256;
    return (int)(b > 2048 ? 2048 : b);
  };
  cast_f32_f16<<<cgrid(nx / 8), 256, 0, stream>>>(x1, x1h, nx / 8);
  cast_f32_f16<<<cgrid(nx / 8), 256, 0, stream>>>(x2, x2h, nx / 8);
  cast_f32_f16<<<cgrid(nx / 8), 256, 0, stream>>>(x3, x3h, nx / 8);
  cast_f32_f16<<<cgrid(nw / 8), 256, 0, stream>>>(Wq, wqh, nw / 8);
  cast_f32_f16<<<cgrid(nw / 8), 256, 0, stream>>>(Wk, wkh, nw / 8);
  cast_f32_f16<<<cgrid(nw / 8), 256, 0, stream>>>(Wv, wvh, nw / 8);

  const dim3 blk(256);
  // Q = x1 Wq^T, K = x2 Wk^T : M=8192 N=1024 K=1024
  gemm_abt<1><<<dim3(64, 8, 1), blk, 0, stream>>>(x1h, wqh, qh, 8192, 1024, 1024, 0, 0, 0);
  gemm_abt<1><<<dim3(64, 8, 1), blk, 0, stream>>>(x2h, wkh, kh, 8192, 1024, 1024, 0, 0, 0);
  // V^T[b][h][s]
  gemm_abt<2><<<dim3(64, 8, 1), blk, 0, stream>>>(x3h, wvh, vth, 8192, 1024, 1024, 0, 0, 0);
  // scores[b] = Q[b] K[b]^T : per-batch 2048x2048x1024, fp32 out
  gemm_abt<0><<<dim3(16, 16, 4), blk, 0, stream>>>(qh, kh, sc, 2048, 2048, 1024,
                                                   (long)S_ * H_, (long)S_ * H_, (long)S_ * S_);
  // P = softmax(scores * 1/sqrt(H) + mask)
  softmax_rows<<<B_ * S_, 256, 0, stream>>>(sc, mask, ph, 0.03125f);
  // out[b] = P[b] (V^T[b])^T : 2048x1024x2048, fp32 to d_out
  gemm_abt<0><<<dim3(16, 8, 4), blk, 0, stream>>>(ph, vth, d_out, 2048, 1024, 2048,
                                                  (long)S_ * S_, (long)S_ * H_, (long)S_ * H_);
}

// Round 2
// 279.116 us; speedup vs baseline: 1.0212x; 1.0212x over previous
//
#include <hip/hip_runtime.h>

typedef _Float16 f16;
typedef _Float16 h8 __attribute__((ext_vector_type(8)));
typedef float f4 __attribute__((ext_vector_type(4)));

typedef const __attribute__((address_space(1))) char gchar;
typedef __attribute__((address_space(3))) char lchar;

#define B_ 4
#define S_ 2048
#define D_ 1024
#define H_ 1024

// ---------------- fp32 -> fp16 cast, vectorized ----------------
__global__ __launch_bounds__(256) void cast_f32_f16(const float* __restrict__ in,
                                                    f16* __restrict__ out, long n8) {
  long i = blockIdx.x * 256L + threadIdx.x;
  const long stride = (long)gridDim.x * 256L;
  for (; i < n8; i += stride) {
    float4 u = *(const float4*)(in + i * 8);
    float4 v = *(const float4*)(in + i * 8 + 4);
    h8 o;
    o[0] = (f16)u.x; o[1] = (f16)u.y; o[2] = (f16)u.z; o[3] = (f16)u.w;
    o[4] = (f16)v.x; o[5] = (f16)v.y; o[6] = (f16)v.z; o[7] = (f16)v.w;
    *(h8*)(out + i * 8) = o;
  }
}

// ---------------- GEMM: C = A * B^T  (m97 structure: global_load_lds w=16, linear LDS) ----------------
// A: [M,K] f16 row-major; B: [N,K] f16 row-major (K contiguous both sides).
// OUT_MODE 0: fp32 C[m*N+n]   (scores, final out)
// OUT_MODE 1: f16  C[m*N+n]   (Q, K projections)
// OUT_MODE 2: f16 transposed per-batch: C[(m>>11)][n][m&2047]  (V^T projection)
#define TILE 128
#define BK 32

template <int OUT_MODE>
__global__ __launch_bounds__(256) void gemm_abt(const f16* __restrict__ A,
                                                const f16* __restrict__ Bm,
                                                void* __restrict__ C,
                                                int M, int N, int K,
                                                long sA, long sB, long sC) {
  const int bz = blockIdx.z;
  A += (long)bz * sA;
  Bm += (long)bz * sB;

  // linear layout [row][k], row stride 32 f16 = 64B (required by global_load_lds)
  __shared__ __align__(16) f16 lA[TILE * BK];
  __shared__ __align__(16) f16 lB[TILE * BK];

  const int tid = threadIdx.x;
  const int lane = tid & 63;
  const int w = tid >> 6;
  const int wr = w >> 1, wc = w & 1;  // 2x2 waves over the 128x128 tile
  const int m0 = blockIdx.x * TILE;
  const int n0 = blockIdx.y * TILE;

  // staging decomposition: one global_load_lds covers 64 lanes x 16B = 16 rows.
  // wave w, chunk c: rows [w*32 + c*16, +16); lane l -> row +(l>>2), col (l&3)*8
  const int lr = lane >> 2;
  const int lc = (lane & 3) * 8;

  const int fr = lane & 15;
  const int kg = (lane >> 4) * 8;

  f4 acc[4][4] = {};

  for (int k0 = 0; k0 < K; k0 += BK) {
    __syncthreads();  // previous iteration's fragment reads complete before overwrite
#pragma unroll
    for (int c = 0; c < 2; ++c) {
      const int br = w * 32 + c * 16;
      __builtin_amdgcn_global_load_lds(
          (gchar*)(A + (long)(m0 + br + lr) * K + k0 + lc),
          (lchar*)&lA[br * BK], 16, 0, 0);
      __builtin_amdgcn_global_load_lds(
          (gchar*)(Bm + (long)(n0 + br + lr) * K + k0 + lc),
          (lchar*)&lB[br * BK], 16, 0, 0);
    }
    __syncthreads();  // compiler drains vmcnt(0) here

    h8 af[4], bf[4];
#pragma unroll
    for (int i = 0; i < 4; ++i) {
      af[i] = *(const h8*)&lA[(wr * 64 + i * 16 + fr) * BK + kg];
      bf[i] = *(const h8*)&lB[(wc * 64 + i * 16 + fr) * BK + kg];
    }
#pragma unroll
    for (int mi = 0; mi < 4; ++mi)
#pragma unroll
      for (int ni = 0; ni < 4; ++ni)
        acc[mi][ni] = __builtin_amdgcn_mfma_f32_16x16x32_f16(af[mi], bf[ni], acc[mi][ni], 0, 0, 0);
  }

  // epilogue: C/D layout (measured): col = lane&15, row = (lane>>4)*4 + reg
  const int fq = (lane >> 4) * 4;
#pragma unroll
  for (int mi = 0; mi < 4; ++mi) {
#pragma unroll
    for (int ni = 0; ni < 4; ++ni) {
#pragma unroll
      for (int i = 0; i < 4; ++i) {
        const int row = m0 + wr * 64 + mi * 16 + fq + i;
        const int col = n0 + wc * 64 + ni * 16 + fr;
        const float val = acc[mi][ni][i];
        if constexpr (OUT_MODE == 0) {
          float* Cp = (float*)C + (long)bz * sC;
          Cp[(long)row * N + col] = val;
        } else if constexpr (OUT_MODE == 1) {
          f16* Cp = (f16*)C + (long)bz * sC;
          Cp[(long)row * N + col] = (f16)val;
        } else {
          f16* Cp = (f16*)C;
          const int b = row >> 11, sr = row & 2047;  // S_=2048 rows per batch
          Cp[((long)b * N + col) * 2048 + sr] = (f16)val;
        }
      }
    }
  }
}

// ---------------- fused scale + mask + softmax, scores f32 -> P f16 ----------------
__global__ __launch_bounds__(256) void softmax_rows(const float* __restrict__ Sc,
                                                    const float* __restrict__ mask,
                                                    f16* __restrict__ P, float scale) {
  const long row = blockIdx.x;  // b*S + q, 8192 rows of length 2048
  const float* s = Sc + row * (long)S_;
  const float* mk = mask + row * (long)S_;
  const int t = threadIdx.x;

  float4 a0 = *(const float4*)(s + t * 8);
  float4 a1 = *(const float4*)(s + t * 8 + 4);
  float4 b0 = *(const float4*)(mk + t * 8);
  float4 b1 = *(const float4*)(mk + t * 8 + 4);
  float v[8] = {a0.x * scale + b0.x, a0.y * scale + b0.y,
                a0.z * scale + b0.z, a0.w * scale + b0.w,
                a1.x * scale + b1.x, a1.y * scale + b1.y,
                a1.z * scale + b1.z, a1.w * scale + b1.w};

  float mx = v[0];
#pragma unroll
  for (int j = 1; j < 8; ++j) mx = fmaxf(mx, v[j]);
  for (int o = 32; o > 0; o >>= 1) mx = fmaxf(mx, __shfl_xor(mx, o));

  __shared__ float redm[4];
  __shared__ float reds[4];
  const int w = t >> 6;
  if ((t & 63) == 0) redm[w] = mx;
  __syncthreads();
  mx = fmaxf(fmaxf(redm[0], redm[1]), fmaxf(redm[2], redm[3]));

  float e[8];
  float sum = 0.f;
#pragma unroll
  for (int j = 0; j < 8; ++j) { e[j] = __expf(v[j] - mx); sum += e[j]; }
  for (int o = 32; o > 0; o >>= 1) sum += __shfl_xor(sum, o);
  if ((t & 63) == 0) reds[w] = sum;
  __syncthreads();
  sum = reds[0] + reds[1] + reds[2] + reds[3];
  const float inv = 1.0f / sum;

  h8 o;
#pragma unroll
  for (int j = 0; j < 8; ++j) o[j] = (f16)(e[j] * inv);
  *(h8*)(P + row * (long)S_ + t * 8) = o;
}

extern "C" void kernel_launch(void* const* d_in, const int* in_sizes, int n_in,
                              void* d_out, int out_size, void* d_ws, size_t ws_size,
                              hipStream_t stream) {
  const float* x1 = (const float*)d_in[0];
  const float* x2 = (const float*)d_in[1];
  const float* x3 = (const float*)d_in[2];
  const float* mask = (const float*)d_in[3];
  const float* Wq = (const float*)d_in[4];
  const float* Wk = (const float*)d_in[5];
  const float* Wv = (const float*)d_in[6];

  const long nx = (long)B_ * S_ * D_;        // 8388608
  const long nw = (long)H_ * D_;             // 1048576
  const long nqkv = (long)B_ * S_ * H_;      // 8388608
  const long nsc = (long)B_ * S_ * S_;       // 16777216

  char* ws = (char*)d_ws;
  f16* x1h = (f16*)ws; ws += nx * 2;
  f16* x2h = (f16*)ws; ws += nx * 2;
  f16* x3h = (f16*)ws; ws += nx * 2;
  f16* wqh = (f16*)ws; ws += nw * 2;
  f16* wkh = (f16*)ws; ws += nw * 2;
  f16* wvh = (f16*)ws; ws += nw * 2;
  f16* qh  = (f16*)ws; ws += nqkv * 2;
  f16* kh  = (f16*)ws; ws += nqkv * 2;
  f16* vth = (f16*)ws; ws += nqkv * 2;   // [b][h][s]
  float* sc = (float*)ws; ws += nsc * 4;
  f16* ph  = (f16*)ws; ws += nsc * 2;    // ~208 MB total

  auto cgrid = [](long n8) {
    long b = (n8 + 255) / 256;
    return (int)(b > 2048 ? 2048 : b);
  };
  cast_f32_f16<<<cgrid(nx / 8), 256, 0, stream>>>(x1, x1h, nx / 8);
  cast_f32_f16<<<cgrid(nx / 8), 256, 0, stream>>>(x2, x2h, nx / 8);
  cast_f32_f16<<<cgrid(nx / 8), 256, 0, stream>>>(x3, x3h, nx / 8);
  cast_f32_f16<<<cgrid(nw / 8), 256, 0, stream>>>(Wq, wqh, nw / 8);
  cast_f32_f16<<<cgrid(nw / 8), 256, 0, stream>>>(Wk, wkh, nw / 8);
  cast_f32_f16<<<cgrid(nw / 8), 256, 0, stream>>>(Wv, wvh, nw / 8);

  const dim3 blk(256);
  // Q = x1 Wq^T, K = x2 Wk^T : M=8192 N=1024 K=1024
  gemm_abt<1><<<dim3(64, 8, 1), blk, 0, stream>>>(x1h, wqh, qh, 8192, 1024, 1024, 0, 0, 0);
  gemm_abt<1><<<dim3(64, 8, 1), blk, 0, stream>>>(x2h, wkh, kh, 8192, 1024, 1024, 0, 0, 0);
  // V^T[b][h][s]
  gemm_abt<2><<<dim3(64, 8, 1), blk, 0, stream>>>(x3h, wvh, vth, 8192, 1024, 1024, 0, 0, 0);
  // scores[b] = Q[b] K[b]^T : per-batch 2048x2048x1024, fp32 out
  gemm_abt<0><<<dim3(16, 16, 4), blk, 0, stream>>>(qh, kh, sc, 2048, 2048, 1024,
                                                   (long)S_ * H_, (long)S_ * H_, (long)S_ * S_);
  // P = softmax(scores * 1/sqrt(H) + mask)
  softmax_rows<<<B_ * S_, 256, 0, stream>>>(sc, mask, ph, 0.03125f);
  // out[b] = P[b] (V^T[b])^T : 2048x1024x2048, fp32 to d_out
  gemm_abt<0><<<dim3(16, 8, 4), blk, 0, stream>>>(ph, vth, d_out, 2048, 1024, 2048,
                                                  (long)S_ * S_, (long)S_ * H_, (long)S_ * H_);
}

// Round 3
// 236.011 us; speedup vs baseline: 1.2077x; 1.1826x over previous
//
#include <hip/hip_runtime.h>

typedef _Float16 f16;
typedef _Float16 h8 __attribute__((ext_vector_type(8)));
typedef float f4 __attribute__((ext_vector_type(4)));

typedef const __attribute__((address_space(1))) char gchar;
typedef __attribute__((address_space(3))) char lchar;

#define B_ 4
#define S_ 2048
#define D_ 1024
#define H_ 1024

// ---------------- fused fp32 -> fp16 cast of all six inputs ----------------
#define NGX (8388608L / 8)  // groups of 8 per x array
#define NGW (1048576L / 8)  // groups of 8 per W array

__global__ __launch_bounds__(256) void cast_all(
    const float* __restrict__ x1, const float* __restrict__ x2, const float* __restrict__ x3,
    const float* __restrict__ wq, const float* __restrict__ wk, const float* __restrict__ wv,
    f16* __restrict__ o1, f16* __restrict__ o2, f16* __restrict__ o3,
    f16* __restrict__ o4, f16* __restrict__ o5, f16* __restrict__ o6) {
  const long NG = 3 * NGX + 3 * NGW;
  long g = blockIdx.x * 256L + threadIdx.x;
  const long stride = (long)gridDim.x * 256L;
  for (; g < NG; g += stride) {
    const float* in;
    f16* out;
    long off;
    if (g < 3 * NGX) {
      const long w = g >> 20;  // NGX = 2^20
      off = (g - w * NGX) * 8;
      in = w == 0 ? x1 : (w == 1 ? x2 : x3);
      out = w == 0 ? o1 : (w == 1 ? o2 : o3);
    } else {
      const long gg = g - 3 * NGX;
      const long h = gg >> 17;  // NGW = 2^17
      off = (gg - h * NGW) * 8;
      in = h == 0 ? wq : (h == 1 ? wk : wv);
      out = h == 0 ? o4 : (h == 1 ? o5 : o6);
    }
    float4 u = *(const float4*)(in + off);
    float4 v = *(const float4*)(in + off + 4);
    h8 o;
    o[0] = (f16)u.x; o[1] = (f16)u.y; o[2] = (f16)u.z; o[3] = (f16)u.w;
    o[4] = (f16)v.x; o[5] = (f16)v.y; o[6] = (f16)v.z; o[7] = (f16)v.w;
    *(h8*)(out + off) = o;
  }
}

// ---------------- GEMM: C = A * B^T  (2-phase dbuf + global_load_lds w=16) ----------------
// A: [M,K] f16 row-major; B: [N,K] f16 row-major (K contiguous both sides).
// OUT_MODE 0: fp32 C[m*N+n]   (scores, final out)
// OUT_MODE 1: f16  C[m*N+n]   (Q, K projections)
// OUT_MODE 2: f16 transposed per-batch: C[(m>>11)][n][m&2047]  (V^T projection)
#define TILE 128
#define BK 32

template <int OUT_MODE>
__global__ __launch_bounds__(256) void gemm_abt(const f16* __restrict__ A,
                                                const f16* __restrict__ Bm,
                                                void* __restrict__ C,
                                                int M, int N, int K,
                                                long sA, long sB, long sC) {
  const int bz = blockIdx.z;
  A += (long)bz * sA;
  Bm += (long)bz * sB;

  // linear layout [buf][row][k], row stride 32 f16 = 64B (required by global_load_lds)
  __shared__ __align__(16) f16 lA[2][TILE * BK];
  __shared__ __align__(16) f16 lB[2][TILE * BK];

  const int tid = threadIdx.x;
  const int lane = tid & 63;
  const int w = tid >> 6;
  const int wr = w >> 1, wc = w & 1;  // 2x2 waves over the 128x128 tile
  const int m0 = blockIdx.x * TILE;
  const int n0 = blockIdx.y * TILE;

  // staging: one global_load_lds covers 64 lanes x 16B = 16 rows of 32 f16.
  const int lr = lane >> 2;
  const int lc = (lane & 3) * 8;
  const f16* Abase = A + (long)(m0 + lr) * K + lc;
  const f16* Bbase = Bm + (long)(n0 + lr) * K + lc;

  const int fr = lane & 15;
  const int kg = (lane >> 4) * 8;

  f4 acc[4][4] = {};

  auto STAGE = [&](int buf, int k0) {
#pragma unroll
    for (int c = 0; c < 2; ++c) {
      const int br = w * 32 + c * 16;  // wave-uniform LDS dest
      __builtin_amdgcn_global_load_lds(
          (gchar*)(Abase + (long)br * K + k0),
          (lchar*)&lA[buf][br * BK], 16, 0, 0);
      __builtin_amdgcn_global_load_lds(
          (gchar*)(Bbase + (long)br * K + k0),
          (lchar*)&lB[buf][br * BK], 16, 0, 0);
    }
  };

  // prologue: fill buf0
  STAGE(0, 0);
  __syncthreads();  // compiler drains vmcnt(0) before barrier

  int cur = 0;
  for (int k0 = 0; k0 < K; k0 += BK) {
    if (k0 + BK < K) STAGE(cur ^ 1, k0 + BK);  // prefetch overlaps this tile's compute

    h8 af[4], bf[4];
#pragma unroll
    for (int i = 0; i < 4; ++i) {
      af[i] = *(const h8*)&lA[cur][(wr * 64 + i * 16 + fr) * BK + kg];
      bf[i] = *(const h8*)&lB[cur][(wc * 64 + i * 16 + fr) * BK + kg];
    }
#pragma unroll
    for (int mi = 0; mi < 4; ++mi)
#pragma unroll
      for (int ni = 0; ni < 4; ++ni)
        acc[mi][ni] = __builtin_amdgcn_mfma_f32_16x16x32_f16(af[mi], bf[ni], acc[mi][ni], 0, 0, 0);

    __syncthreads();  // one vmcnt(0)+barrier per tile: prefetch landed, reads done
    cur ^= 1;
  }

  // epilogue: C/D layout (measured): col = lane&15, row = (lane>>4)*4 + reg
  const int fq = (lane >> 4) * 4;
#pragma unroll
  for (int mi = 0; mi < 4; ++mi) {
#pragma unroll
    for (int ni = 0; ni < 4; ++ni) {
#pragma unroll
      for (int i = 0; i < 4; ++i) {
        const int row = m0 + wr * 64 + mi * 16 + fq + i;
        const int col = n0 + wc * 64 + ni * 16 + fr;
        const float val = acc[mi][ni][i];
        if constexpr (OUT_MODE == 0) {
          float* Cp = (float*)C + (long)bz * sC;
          Cp[(long)row * N + col] = val;
        } else if constexpr (OUT_MODE == 1) {
          f16* Cp = (f16*)C + (long)bz * sC;
          Cp[(long)row * N + col] = (f16)val;
        } else {
          f16* Cp = (f16*)C;
          const int b = row >> 11, sr = row & 2047;  // S_=2048 rows per batch
          Cp[((long)b * N + col) * 2048 + sr] = (f16)val;
        }
      }
    }
  }
}

// ---------------- fused scale + mask + softmax, scores f32 -> P f16 ----------------
__global__ __launch_bounds__(256) void softmax_rows(const float* __restrict__ Sc,
                                                    const float* __restrict__ mask,
                                                    f16* __restrict__ P, float scale) {
  const long row = blockIdx.x;  // b*S + q, 8192 rows of length 2048
  const float* s = Sc + row * (long)S_;
  const float* mk = mask + row * (long)S_;
  const int t = threadIdx.x;

  float4 a0 = *(const float4*)(s + t * 8);
  float4 a1 = *(const float4*)(s + t * 8 + 4);
  float4 b0 = *(const float4*)(mk + t * 8);
  float4 b1 = *(const float4*)(mk + t * 8 + 4);
  float v[8] = {a0.x * scale + b0.x, a0.y * scale + b0.y,
                a0.z * scale + b0.z, a0.w * scale + b0.w,
                a1.x * scale + b1.x, a1.y * scale + b1.y,
                a1.z * scale + b1.z, a1.w * scale + b1.w};

  float mx = v[0];
#pragma unroll
  for (int j = 1; j < 8; ++j) mx = fmaxf(mx, v[j]);
  for (int o = 32; o > 0; o >>= 1) mx = fmaxf(mx, __shfl_xor(mx, o));

  __shared__ float redm[4];
  __shared__ float reds[4];
  const int w = t >> 6;
  if ((t & 63) == 0) redm[w] = mx;
  __syncthreads();
  mx = fmaxf(fmaxf(redm[0], redm[1]), fmaxf(redm[2], redm[3]));

  float e[8];
  float sum = 0.f;
#pragma unroll
  for (int j = 0; j < 8; ++j) { e[j] = __expf(v[j] - mx); sum += e[j]; }
  for (int o = 32; o > 0; o >>= 1) sum += __shfl_xor(sum, o);
  if ((t & 63) == 0) reds[w] = sum;
  __syncthreads();
  sum = reds[0] + reds[1] + reds[2] + reds[3];
  const float inv = 1.0f / sum;

  h8 o;
#pragma unroll
  for (int j = 0; j < 8; ++j) o[j] = (f16)(e[j] * inv);
  *(h8*)(P + row * (long)S_ + t * 8) = o;
}

extern "C" void kernel_launch(void* const* d_in, const int* in_sizes, int n_in,
                              void* d_out, int out_size, void* d_ws, size_t ws_size,
                              hipStream_t stream) {
  const float* x1 = (const float*)d_in[0];
  const float* x2 = (const float*)d_in[1];
  const float* x3 = (const float*)d_in[2];
  const float* mask = (const float*)d_in[3];
  const float* Wq = (const float*)d_in[4];
  const float* Wk = (const float*)d_in[5];
  const float* Wv = (const float*)d_in[6];

  const long nx = (long)B_ * S_ * D_;        // 8388608
  const long nw = (long)H_ * D_;             // 1048576
  const long nqkv = (long)B_ * S_ * H_;      // 8388608
  const long nsc = (long)B_ * S_ * S_;       // 16777216

  char* ws = (char*)d_ws;
  f16* x1h = (f16*)ws; ws += nx * 2;
  f16* x2h = (f16*)ws; ws += nx * 2;
  f16* x3h = (f16*)ws; ws += nx * 2;
  f16* wqh = (f16*)ws; ws += nw * 2;
  f16* wkh = (f16*)ws; ws += nw * 2;
  f16* wvh = (f16*)ws; ws += nw * 2;
  f16* qh  = (f16*)ws; ws += nqkv * 2;
  f16* kh  = (f16*)ws; ws += nqkv * 2;
  f16* vth = (f16*)ws; ws += nqkv * 2;   // [b][h][s]
  float* sc = (float*)ws; ws += nsc * 4;
  f16* ph  = (f16*)ws; ws += nsc * 2;    // ~208 MB total

  cast_all<<<2048, 256, 0, stream>>>(x1, x2, x3, Wq, Wk, Wv,
                                     x1h, x2h, x3h, wqh, wkh, wvh);

  const dim3 blk(256);
  // Q = x1 Wq^T, K = x2 Wk^T : M=8192 N=1024 K=1024
  gemm_abt<1><<<dim3(64, 8, 1), blk, 0, stream>>>(x1h, wqh, qh, 8192, 1024, 1024, 0, 0, 0);
  gemm_abt<1><<<dim3(64, 8, 1), blk, 0, stream>>>(x2h, wkh, kh, 8192, 1024, 1024, 0, 0, 0);
  // V^T[b][h][s]
  gemm_abt<2><<<dim3(64, 8, 1), blk, 0, stream>>>(x3h, wvh, vth, 8192, 1024, 1024, 0, 0, 0);
  // scores[b] = Q[b] K[b]^T : per-batch 2048x2048x1024, fp32 out
  gemm_abt<0><<<dim3(16, 16, 4), blk, 0, stream>>>(qh, kh, sc, 2048, 2048, 1024,
                                                   (long)S_ * H_, (long)S_ * H_, (long)S_ * S_);
  // P = softmax(scores * 1/sqrt(H) + mask)
  softmax_rows<<<B_ * S_, 256, 0, stream>>>(sc, mask, ph, 0.03125f);
  // out[b] = P[b] (V^T[b])^T : 2048x1024x2048, fp32 to d_out
  gemm_abt<0><<<dim3(16, 8, 4), blk, 0, stream>>>(ph, vth, d_out, 2048, 1024, 2048,
                                                  (long)S_ * S_, (long)S_ * H_, (long)S_ * H_);
}